// Round 5
// baseline (201.445 us; speedup 1.0000x reference)
//
#include <hip/hip_runtime.h>

#define NBINS   100
#define NDW     51    // bin-pair dwords per column: bins 0..101 (100=spill, 101=pad)
#define BLK     64    // one wave per block; column == lane (exclusive, no atomics)
#define GRID    3072  // 12 blocks/CU × 256 CU  (LDS 13.3 KB/block → 12 resident)

typedef __fp16 half2v __attribute__((ext_vector_type(2)));

// ---------------------------------------------------------------------------
// Kernel 1: zero the global bin accumulator in d_ws (poisoned 0xAA once).
// ---------------------------------------------------------------------------
__global__ void histo_zero(float* __restrict__ g) {
    int i = threadIdx.x;
    if (i < NBINS) g[i] = 0.0f;
}

// ---------------------------------------------------------------------------
// Kernel 2: streaming pass. Per-lane column of 51 u32, each holding fp16 bins
// (2j, 2j+1). Taps (k, k+1) live in dwords j=k>>1 and j+1:
//   k even: d[j]   += pack(w0, w1)            d[j+1] += 0
//   k odd : d[j]   += pack(0,  w0)            d[j+1] += pack(w1, 0)
// built from one cvt_pkrtz ph = (w0lo, w1hi):  odd ? ph<<16 : ph
//                                              odd ? ph>>16 : 0
// One ds_read2_b32 + 2x v_pk_add_f16 + one ds_write2_b32 per element.
// Column = 204 B -> 12 waves/CU (vs 6 with fp32 columns): halves the per-wave
// serialized RMW chain (341 elem x ~130cyc = 19us) to under the HBM floor.
// ---------------------------------------------------------------------------
__global__ __launch_bounds__(BLK) void histo_accum(const float* __restrict__ x,
                                                   float* __restrict__ gbins,
                                                   int n4, int n) {
    __shared__ unsigned int h[NDW * BLK];
    const int lane = threadIdx.x;

    for (int i = lane; i < NDW * BLK; i += BLK) h[i] = 0u;
    __syncthreads();

#define PROC(v)                                                         \
    {                                                                   \
        float xf = (v) * 100.0f;                                        \
        float fk = floorf(xf);                                          \
        int   k  = min((int)fk, NBINS - 1);                             \
        float w1 = (xf - fk) * 0.01f;                                   \
        float w0 = 0.01f - w1;                                          \
        half2v phv = __builtin_amdgcn_cvt_pkrtz(w0, w1);                \
        unsigned int p = __builtin_bit_cast(unsigned int, phv);         \
        int  j   = k >> 1;                                              \
        bool odd = (k & 1) != 0;                                        \
        unsigned int a0 = odd ? (p << 16) : p;                          \
        unsigned int a1 = odd ? (p >> 16) : 0u;                         \
        int idx = j * BLK + lane;                                       \
        unsigned int d0 = h[idx];                                       \
        unsigned int d1 = h[idx + BLK];                                 \
        half2v r0 = __builtin_bit_cast(half2v, d0) +                    \
                    __builtin_bit_cast(half2v, a0);                     \
        half2v r1 = __builtin_bit_cast(half2v, d1) +                    \
                    __builtin_bit_cast(half2v, a1);                     \
        h[idx]       = __builtin_bit_cast(unsigned int, r0);            \
        h[idx + BLK] = __builtin_bit_cast(unsigned int, r1);            \
    }

#define PROC4(v) { PROC((v).x); PROC((v).y); PROC((v).z); PROC((v).w); }

    const float4* __restrict__ x4 = (const float4*)x;
    const int stride = gridDim.x * BLK;
    int i = blockIdx.x * BLK + lane;

    // 4 independent float4 loads in flight per wave
    for (; i + 3 * stride < n4; i += 4 * stride) {
        float4 a = x4[i];
        float4 b = x4[i + stride];
        float4 c = x4[i + 2 * stride];
        float4 d = x4[i + 3 * stride];
        PROC4(a); PROC4(b); PROC4(c); PROC4(d);
    }
    for (; i < n4; i += stride) {
        float4 a = x4[i];
        PROC4(a);
    }

    // scalar tail (n % 4) — block 0 only
    if (blockIdx.x == 0) {
        for (int t = n4 * 4 + lane; t < n; t += BLK) {
            float v = x[t];
            PROC(v);
        }
    }
#undef PROC4
#undef PROC

    __syncthreads();

    // Reduce 64 columns per bin-pair in fp32. Lane j owns dword-row j
    // (bins 2j, 2j+1); j=50 is the spill row (bins 100,101) -> skipped.
    // Diagonal sweep: bank = (c+lane)%32, 2-way (free).
    if (lane < NDW - 1) {
        int j = lane;
        float s0 = 0.0f, s1 = 0.0f;
#pragma unroll
        for (int c = 0; c < BLK; ++c) {
            int cc = (c + lane) & (BLK - 1);
            unsigned int u = h[j * BLK + cc];
            half2v hv = __builtin_bit_cast(half2v, u);
            s0 += (float)hv.x;
            s1 += (float)hv.y;
        }
        unsafeAtomicAdd(&gbins[2 * j],     s0);
        unsafeAtomicAdd(&gbins[2 * j + 1], s1);
    }
}

// ---------------------------------------------------------------------------
// Kernel 3: normalize — out[i] = g[i] / (sum(g) + 1e-6). One block, 128 thr.
// ---------------------------------------------------------------------------
__global__ void histo_final(const float* __restrict__ g, float* __restrict__ out) {
    __shared__ float wsum[2];
    const int t = threadIdx.x;           // 128 threads = 2 waves
    float v = (t < NBINS) ? g[t] : 0.0f;

    float s = v;
#pragma unroll
    for (int o = 32; o > 0; o >>= 1) s += __shfl_down(s, o, 64);
    if ((t & 63) == 0) wsum[t >> 6] = s;
    __syncthreads();

    float total = wsum[0] + wsum[1];
    if (t < NBINS) out[t] = v / (total + 1e-6f);
}

extern "C" void kernel_launch(void* const* d_in, const int* in_sizes, int n_in,
                              void* d_out, int out_size, void* d_ws, size_t ws_size,
                              hipStream_t stream) {
    const float* x   = (const float*)d_in[0];  // [64 * 1048576] fp32 in [0,1)
    float*       out = (float*)d_out;          // [100] fp32
    float*       g   = (float*)d_ws;           // 100-float accumulator

    const int n  = in_sizes[0];
    const int n4 = n / 4;

    histo_zero<<<1, 128, 0, stream>>>(g);

    int blocks = GRID;                          // 12 blocks/CU (13.3 KB LDS each)
    int need   = (n4 + BLK - 1) / BLK;
    if (blocks > need) blocks = need;
    histo_accum<<<blocks, BLK, 0, stream>>>(x, g, n4, n);

    histo_final<<<1, 128, 0, stream>>>(g, out);
}

// Round 6
// 56.547 us; speedup vs baseline: 3.5624x; 3.5624x over previous
//
#include <hip/hip_runtime.h>

#define NBINS 100
#define NROWS 101          // row 100 = spill slot for x -> 1.0 boundary (discarded)
#define BLK   64           // one wave per block; column == lane (exclusive)
#define GRID  1536         // 6 blocks/CU (LDS 25856 B/block)
#define REP   8            // global accumulator replicas (atomic contention relief)

typedef unsigned int       u32;
typedef unsigned long long u64;

// Per-element: u = round(x*102400) -> k = u>>10 (bin), ti = u&1023 (frac in 1/1024).
// Column cell (u32): (N << 20) + sum(ti).  Per-lane <=684 elems -> T < 2^20, no carry.
// Global cell (u64): (N << 37) + T_total.  N_tot <= 2^26 (27 bits), T_tot <= 2^36 (37 bits).
// Finalize: count[b] = 0.01 * (N_b - T_b/1024 + T_{b-1}/1024); out = count / (sum+1e-6).

__global__ void histo_zero(u64* __restrict__ g) {
    int i = blockIdx.x * blockDim.x + threadIdx.x;
    if (i < REP * NBINS) g[i] = 0ull;
}

__global__ __launch_bounds__(BLK) void histo_accum(const float* __restrict__ x,
                                                   u64* __restrict__ g,
                                                   int n4, int n) {
    __shared__ u32 h[NROWS * BLK];
    const int lane = threadIdx.x;

    for (int i = lane; i < NROWS * BLK; i += BLK) h[i] = 0u;
    __syncthreads();

// Two elements per batch: both reads issue before either write (one LDS round
// trip per 2 elements). Same-bin collision merged in registers beforehand so
// "last write wins" is correct (both lanes read the same stale base).
#define PROC2(va, vb) {                                        \
        u32 u0 = (u32)((va) * 102400.0f + 0.5f);               \
        u32 u1 = (u32)((vb) * 102400.0f + 0.5f);               \
        u32 k0 = u0 >> 10, k1 = u1 >> 10;                      \
        u32 w0 = (1u << 20) + (u0 & 1023u);                    \
        u32 w1 = (1u << 20) + (u1 & 1023u);                    \
        bool eq = (k0 == k1);                                  \
        u32 w1m = w1 + (eq ? w0 : 0u);                         \
        u32 w0m = eq ? 0u : w0;                                \
        int a0 = (int)(k0 * BLK) + lane;                       \
        int a1 = (int)(k1 * BLK) + lane;                       \
        u32 d0 = h[a0];                                        \
        u32 d1 = h[a1];                                        \
        h[a0] = d0 + w0m;                                      \
        h[a1] = d1 + w1m;                                      \
    }

#define PROC1(va) {                                            \
        u32 u0 = (u32)((va) * 102400.0f + 0.5f);               \
        u32 k0 = u0 >> 10;                                     \
        int a0 = (int)(k0 * BLK) + lane;                       \
        h[a0] += (1u << 20) + (u0 & 1023u);                    \
    }

#define PROC2x2(v) { PROC2((v).x, (v).y); PROC2((v).z, (v).w); }

    const float4* __restrict__ x4 = (const float4*)x;
    const int stride = gridDim.x * BLK;
    int i = blockIdx.x * BLK + lane;

    // 8 float4 loads in flight per lane (128 B) — HBM latency amortized over
    // 16 LDS-chain batches (~2000 cyc) per iteration.
    for (; i + 7 * stride < n4; i += 8 * stride) {
        float4 v0 = x4[i];
        float4 v1 = x4[i + 1 * stride];
        float4 v2 = x4[i + 2 * stride];
        float4 v3 = x4[i + 3 * stride];
        float4 v4 = x4[i + 4 * stride];
        float4 v5 = x4[i + 5 * stride];
        float4 v6 = x4[i + 6 * stride];
        float4 v7 = x4[i + 7 * stride];
        PROC2x2(v0); PROC2x2(v1); PROC2x2(v2); PROC2x2(v3);
        PROC2x2(v4); PROC2x2(v5); PROC2x2(v6); PROC2x2(v7);
    }
    for (; i < n4; i += stride) {
        float4 v = x4[i];
        PROC2x2(v);
    }
    if (blockIdx.x == 0) {               // scalar tail (n % 4)
        for (int t = n4 * 4 + lane; t < n; t += BLK) PROC1(x[t]);
    }
#undef PROC2x2
#undef PROC1
#undef PROC2

    __syncthreads();

    // Reduce 64 columns/bin (diagonal sweep: bank = (c+lane)%32, 2-way = free),
    // unpack, repack as u64, one global atomic per bin per block (8 replicas).
    u64* grep = &g[(blockIdx.x & (REP - 1)) * NBINS];
    for (int b = lane; b < NBINS; b += BLK) {
        u32 Ns = 0, Ts = 0;
#pragma unroll
        for (int c = 0; c < BLK; ++c) {
            int cc = (c + lane) & (BLK - 1);
            u32 u = h[b * BLK + cc];
            Ns += u >> 20;
            Ts += u & 0xFFFFFu;
        }
        atomicAdd(&grep[b], ((u64)Ns << 37) + (u64)Ts);
    }
}

__global__ void histo_final(const u64* __restrict__ g, float* __restrict__ out) {
    __shared__ float Tprev[NBINS + 1];
    __shared__ float wsum[2];
    const int t = threadIdx.x;           // 128 threads = 2 waves

    float N = 0.0f, T = 0.0f;
    if (t < NBINS) {
        u64 acc = 0ull;
#pragma unroll
        for (int r = 0; r < REP; ++r) acc += g[r * NBINS + t];
        N = (float)(acc >> 37);
        T = (float)(acc & ((1ull << 37) - 1ull));
        Tprev[t + 1] = T;
    }
    if (t == 127) Tprev[0] = 0.0f;
    __syncthreads();

    float c = 0.0f;
    if (t < NBINS) c = 0.01f * (N + (Tprev[t] - T) * (1.0f / 1024.0f));

    float s = c;
#pragma unroll
    for (int o = 32; o > 0; o >>= 1) s += __shfl_down(s, o, 64);
    if ((t & 63) == 0) wsum[t >> 6] = s;
    __syncthreads();

    float total = wsum[0] + wsum[1];
    if (t < NBINS) out[t] = c / (total + 1e-6f);
}

extern "C" void kernel_launch(void* const* d_in, const int* in_sizes, int n_in,
                              void* d_out, int out_size, void* d_ws, size_t ws_size,
                              hipStream_t stream) {
    const float* x   = (const float*)d_in[0];  // [64 * 1048576] fp32 in [0,1)
    float*       out = (float*)d_out;          // [100] fp32
    u64*         g   = (u64*)d_ws;             // REP*100 u64 accumulators (6.4 KB)

    const int n  = in_sizes[0];
    const int n4 = n / 4;

    histo_zero<<<(REP * NBINS + 255) / 256, 256, 0, stream>>>(g);

    int blocks = GRID;
    int need   = (n4 + BLK - 1) / BLK;
    if (blocks > need) blocks = need;
    histo_accum<<<blocks, BLK, 0, stream>>>(x, g, n4, n);

    histo_final<<<1, 128, 0, stream>>>(g, out);
}